// Round 9
// baseline (127.330 us; speedup 1.0000x reference)
//
#include <hip/hip_runtime.h>
#include <math.h>

// StructureLoss: B=32, C=1, H=W=512, 31x31 box filter, pad 15
#define BB 32
#define HH 512
#define WW 512
#define KK 31
#define PP 15
#define SEGR 64                          // output rows per block
#define SCOLS 256                        // output cols per strip
#define LCOLS 288                        // 16 + 256 + 16 halo cols in LDS
#define RING 33                          // ring depth; 33 avoids slot collision
#define NBLOCKS (BB * 2 * (HH / SEGR))   // 32 img x 2 strips x 8 segs = 512
#define NTHREADS 256

__device__ inline float wave_reduce(float v) {
    #pragma unroll
    for (int off = 32; off > 0; off >>= 1) v += __shfl_down(v, off);
    return v;
}

// 3 transcendentals/px: e=exp(-|x|), r=rcp(1+e) -> sigmoid = r or 1-r,
// log1p(e) = -log(r)
__device__ inline void accum_px(float s, float tg, float x,
                                float& aw, float& ab, float& ai, float& au) {
    const float inv = 1.0f / (float)(KK * KK);
    float pooled = s * inv;
    float weit = fmaf(5.0f, fabsf(pooled - tg), 1.0f);
    float e  = __expf(-fabsf(x));
    float rr = __builtin_amdgcn_rcpf(1.0f + e);
    float bce = fmaxf(x, 0.0f) - x * tg - __logf(rr);
    float p  = (x >= 0.0f) ? rr : (1.0f - rr);
    aw += weit;
    ab = fmaf(weit, bce, ab);
    ai = fmaf(p * tg, weit, ai);
    au = fmaf(p + tg, weit, au);
}

__global__ __launch_bounds__(NTHREADS, 2) void structure_loss_main(
    const float* __restrict__ pred, const float* __restrict__ target,
    float* __restrict__ partials /* [NBLOCKS][4] */)
{
    __shared__ float ring[RING][LCOLS];   // raw target rows (33-deep ring)
    __shared__ float vsl[LCOLS];          // vertical 31-row sums per col
    __shared__ float red[16];

    const int t     = threadIdx.x;
    const int blk   = blockIdx.x;
    const int b     = blk >> 4;           // 16 blocks per image
    const int strip = (blk >> 3) & 1;
    const int seg   = blk & 7;
    const int y0    = seg * SEGR;
    const int x0    = strip * SCOLS;

    const float* tb = target + (size_t)b * HH * WW;
    const float* pb = pred   + (size_t)b * HH * WW;

    // ---- init: load rows [y0-15, y0+16] (32 rows x 288 cols) into ring ----
    // 32 rows x 72 float4 = 2304 loads; idx = t + 256k, k < 9
    #pragma unroll
    for (int k = 0; k < 9; ++k) {
        int idx  = t + 256 * k;
        int row  = idx / 72;              // 0..31 (const divisor -> magic mul)
        int c4   = idx - row * 72;        // 0..71
        int y    = y0 - PP + row;
        int slot = (y + RING) % RING;     // y >= -15 so y+33 > 0
        int cbase = x0 - 16 + 4 * c4;     // image col of .x
        bool cok = (strip == 0) ? (c4 >= 4) : (c4 <= 67);  // whole-f4 col mask
        float4 v = make_float4(0.f, 0.f, 0.f, 0.f);
        if (y >= 0 && y < HH && cok)
            v = *(const float4*)(tb + (size_t)y * WW + cbase);
        *(float4*)&ring[slot][4 * c4] = v;
    }
    __syncthreads();

    // ---- vsl init: sum rows [y0-15, y0+15] per col (halo cols included) ----
    {
        int sl = (y0 - PP + RING) % RING;
        float s1 = 0.f, s2 = 0.f;
        int j2 = 256 + (t & 31);          // clamped so all threads read in-bounds
        #pragma unroll
        for (int rr = 0; rr < 31; ++rr) {
            s1 += ring[sl][t];
            s2 += ring[sl][j2];
            sl = (sl + 1 == RING) ? 0 : sl + 1;
        }
        vsl[t] = s1;
        if (t < 32) vsl[256 + t] = s2;
    }
    __syncthreads();

    // ring slots for current row y = y0 + r
    int s_tg  = y0 % RING;                  // row y      (pointwise target)
    int s_add = (y0 + 16) % RING;           // row y+16   (enters window)
    int s_sub = (y0 - PP + RING) % RING;    // row y-15   (leaves window)
    int s_wr  = (y0 + 17) % RING;           // row y+17   (incoming prefetch)

    float aw = 0.f, ab_ = 0.f, ai = 0.f, au = 0.f;

    for (int r = 0; r < SEGR; ++r) {
        const int y = y0 + r;

        // ---- phase A: prefetch + taps + accumulate ----
        float4 pf = make_float4(0.f, 0.f, 0.f, 0.f);
        if (t < 72) {                       // prefetch row y+17 into regs
            int yy = y + 17;
            int cbase = x0 - 16 + 4 * t;
            bool cok = (strip == 0) ? (t >= 4) : (t <= 67);
            if (yy < HH && cok)
                pf = *(const float4*)(tb + (size_t)yy * WW + cbase);
        }
        float prv = pb[(size_t)y * WW + x0 + t];   // pred, read once

        float s = 0.f;                      // horizontal 31-tap window on vsl
        #pragma unroll
        for (int j = 1; j <= 31; ++j) s += vsl[t + j];
        float tgv = ring[s_tg][t + 16];     // target, from LDS (read once ever)
        accum_px(s, tgv, prv, aw, ab_, ai, au);
        __syncthreads();

        // ---- phase B: slide vertical window in LDS, commit prefetched row ----
        {
            float vadd = ring[s_add][t];
            float vsub = ring[s_sub][t];
            vsl[t] += vadd - vsub;
            if (t < 32) {
                float va2 = ring[s_add][256 + t];
                float vs2 = ring[s_sub][256 + t];
                vsl[256 + t] += va2 - vs2;
            }
            if (t < 72) *(float4*)&ring[s_wr][4 * t] = pf;
        }
        __syncthreads();

        s_tg  = (s_tg  + 1 == RING) ? 0 : s_tg  + 1;
        s_add = (s_add + 1 == RING) ? 0 : s_add + 1;
        s_sub = (s_sub + 1 == RING) ? 0 : s_sub + 1;
        s_wr  = (s_wr  + 1 == RING) ? 0 : s_wr  + 1;
    }

    // ---- block reduction ----
    aw  = wave_reduce(aw);
    ab_ = wave_reduce(ab_);
    ai  = wave_reduce(ai);
    au  = wave_reduce(au);
    const int wave = t >> 6;
    const int lane = t & 63;
    if (lane == 0) {
        red[wave * 4 + 0] = aw;
        red[wave * 4 + 1] = ab_;
        red[wave * 4 + 2] = ai;
        red[wave * 4 + 3] = au;
    }
    __syncthreads();
    if (t == 0) {
        float w = 0.f, bc = 0.f, in = 0.f, un = 0.f;
        #pragma unroll
        for (int i = 0; i < 4; ++i) {
            w  += red[i * 4 + 0];
            bc += red[i * 4 + 1];
            in += red[i * 4 + 2];
            un += red[i * 4 + 3];
        }
        float* o = partials + (size_t)blk * 4;
        o[0] = w; o[1] = bc; o[2] = in; o[3] = un;
    }
}

__global__ __launch_bounds__(256) void structure_loss_finalize(
    const float* __restrict__ partials, float* __restrict__ out)
{
    // partials: [512][4]; image b owns entries [b*16, (b+1)*16)
    const int t  = threadIdx.x;      // 256 threads
    const int b  = t >> 3;           // image 0..31  (8 threads per image)
    const int i0 = (t & 7) * 2;      // 2 partial-entries per thread
    float w = 0.f, bc = 0.f, in = 0.f, un = 0.f;
    #pragma unroll
    for (int k = 0; k < 2; ++k) {
        float4 v = *(const float4*)(partials + ((size_t)(b * 16 + i0 + k)) * 4);
        w += v.x; bc += v.y; in += v.z; un += v.w;
    }
    #pragma unroll
    for (int off = 4; off > 0; off >>= 1) {
        w  += __shfl_down(w, off);
        bc += __shfl_down(bc, off);
        in += __shfl_down(in, off);
        un += __shfl_down(un, off);
    }
    __shared__ float vals[32];
    if ((t & 7) == 0) {
        float wbce = bc / w;
        float wiou = 1.0f - (in + 1.0f) / (un - in + 1.0f);
        vals[b] = wbce + wiou;
    }
    __syncthreads();
    if (t < 64) {
        float v = (t < 32) ? vals[t] : 0.0f;
        v = wave_reduce(v);
        if (t == 0) out[0] = v / (float)BB;
    }
}

extern "C" void kernel_launch(void* const* d_in, const int* in_sizes, int n_in,
                              void* d_out, int out_size, void* d_ws, size_t ws_size,
                              hipStream_t stream) {
    const float* pred   = (const float*)d_in[0];
    const float* target = (const float*)d_in[1];
    float* out      = (float*)d_out;
    float* partials = (float*)d_ws;   // NBLOCKS*4 floats = 8 KB

    structure_loss_main<<<NBLOCKS, NTHREADS, 0, stream>>>(pred, target, partials);
    structure_loss_finalize<<<1, 256, 0, stream>>>(partials, out);
}

// Round 10
// 116.611 us; speedup vs baseline: 1.0919x; 1.0919x over previous
//
#include <hip/hip_runtime.h>
#include <math.h>

// StructureLoss: B=32, C=1, H=W=512, 31x31 box filter, pad 15
#define BB 32
#define HH 512
#define WW 512
#define KK 31
#define PP 15

#define A_NBLK (BB * 8)                // pass A: 8 row-segments of 64 per image
#define B_NBLK (BB * (HH / 4))         // pass B: 4096 blocks, wave = 1 row

__device__ inline float wave_reduce(float v) {
    #pragma unroll
    for (int off = 32; off > 0; off >>= 1) v += __shfl_down(v, off);
    return v;
}

// 3 transcendentals/px: e=exp(-|x|), r=rcp(1+e) -> sigmoid = r or 1-r,
// log1p(e) = -log(r)
__device__ inline void accum_px(float s, float tg, float x,
                                float& aw, float& ab, float& ai, float& au) {
    const float inv = 1.0f / (float)(KK * KK);
    float pooled = s * inv;
    float weit = fmaf(5.0f, fabsf(pooled - tg), 1.0f);
    float e  = __expf(-fabsf(x));
    float rr = __builtin_amdgcn_rcpf(1.0f + e);
    float bce = fmaxf(x, 0.0f) - x * tg - __logf(rr);
    float p  = (x >= 0.0f) ? rr : (1.0f - rr);
    aw += weit;
    ab = fmaf(weit, bce, ab);
    ai = fmaf(p * tg, weit, ai);
    au = fmaf(p + tg, weit, au);
}

__device__ inline float4 f4add(float4 a, float4 b) {
    return make_float4(a.x + b.x, a.y + b.y, a.z + b.z, a.w + b.w);
}
__device__ inline float4 f4addsub(float4 s, float4 a, float4 b) {
    return make_float4(s.x + a.x - b.x, s.y + a.y - b.y,
                       s.z + a.z - b.z, s.w + a.w - b.w);
}

// ---------------- Pass A: vertical 31-row box sum -> V in d_ws ----------------
// 256 blocks x 256 thr; thread owns 4 cols; block = two stacked 32-row groups
// (halo rows shared through L1). No barriers, deep unroll for MLP.
__global__ __launch_bounds__(256) void vsum_kernel(
    const float* __restrict__ target, float* __restrict__ V)
{
    const int t   = threadIdx.x;
    const int g   = t >> 7;            // row-group 0/1
    const int i   = t & 127;
    const int c   = 4 * i;             // col of .x
    const int blk = blockIdx.x;        // 32 img x 8 seg
    const int b   = blk >> 3;
    const int seg = blk & 7;
    const int y0  = seg * 64 + g * 32; // group's out-rows [y0, y0+32)

    const float* tb = target + (size_t)b * HH * WW + c;
    float*       vb = V      + (size_t)b * HH * WW + c;

    const bool interior = (y0 != 0) && (y0 != 480);  // wave-uniform

    float4 s;
    if (interior) {
        // init: rows [y0-15, y0+15], 4 independent chains
        float4 a0 = make_float4(0,0,0,0), a1 = a0, a2 = a0, a3 = a0;
        #pragma unroll
        for (int j = 0; j < 28; j += 4) {
            a0 = f4add(a0, *(const float4*)(tb + (size_t)(y0 - 15 + j) * WW));
            a1 = f4add(a1, *(const float4*)(tb + (size_t)(y0 - 14 + j) * WW));
            a2 = f4add(a2, *(const float4*)(tb + (size_t)(y0 - 13 + j) * WW));
            a3 = f4add(a3, *(const float4*)(tb + (size_t)(y0 - 12 + j) * WW));
        }
        a0 = f4add(a0, *(const float4*)(tb + (size_t)(y0 + 13) * WW));
        a1 = f4add(a1, *(const float4*)(tb + (size_t)(y0 + 14) * WW));
        a2 = f4add(a2, *(const float4*)(tb + (size_t)(y0 + 15) * WW));
        s = f4add(f4add(a0, a1), f4add(a2, a3));

        // steady: unroll 8, loads hoisted -> 16 loads in flight per chunk
        #pragma unroll
        for (int r = 0; r < 32; r += 8) {
            float4 ad[8], sb[8];
            #pragma unroll
            for (int k = 0; k < 8; ++k) {
                ad[k] = *(const float4*)(tb + (size_t)(y0 + r + k + 16) * WW);
                sb[k] = *(const float4*)(tb + (size_t)(y0 + r + k - 15) * WW);
            }
            #pragma unroll
            for (int k = 0; k < 8; ++k) {
                *(float4*)(vb + (size_t)(y0 + r + k) * WW) = s;
                s = f4addsub(s, ad[k], sb[k]);
            }
        }
    } else {
        // edge groups (y0==0 or y0==480): clamp+zero-select on row index
        float4 a0 = make_float4(0,0,0,0), a1 = a0, a2 = a0, a3 = a0;
        #pragma unroll
        for (int j = -PP; j <= PP; ++j) {
            int y  = y0 + j;
            int yc = min(max(y, 0), HH - 1);
            float4 v = *(const float4*)(tb + (size_t)yc * WW);
            if (y < 0 || y >= HH) v = make_float4(0,0,0,0);
            switch (j & 3) {
                case 0: a0 = f4add(a0, v); break;
                case 1: a1 = f4add(a1, v); break;
                case 2: a2 = f4add(a2, v); break;
                default: a3 = f4add(a3, v); break;
            }
        }
        s = f4add(f4add(a0, a1), f4add(a2, a3));
        #pragma unroll
        for (int r = 0; r < 32; r += 8) {
            float4 ad[8], sb[8];
            #pragma unroll
            for (int k = 0; k < 8; ++k) {
                int ya = y0 + r + k + 16;
                int ys = y0 + r + k - 15;
                float4 va = *(const float4*)(tb + (size_t)min(ya, HH - 1) * WW);
                float4 vs = *(const float4*)(tb + (size_t)max(ys, 0) * WW);
                if (ya >= HH) va = make_float4(0,0,0,0);
                if (ys < 0)   vs = make_float4(0,0,0,0);
                ad[k] = va; sb[k] = vs;
            }
            #pragma unroll
            for (int k = 0; k < 8; ++k) {
                *(float4*)(vb + (size_t)(y0 + r + k) * WW) = s;
                s = f4addsub(s, ad[k], sb[k]);
            }
        }
    }
}

// ------- Pass B: per-row horizontal 31-window via shuffles + loss accum -------
// (verbatim from R7 -- validated absmax 0)
__device__ inline float4 ld4(const float* base, int c) {
    return *(const float4*)(base + c);
}

__global__ __launch_bounds__(256) void loss_kernel(
    const float* __restrict__ pred, const float* __restrict__ target,
    const float* __restrict__ V, float* __restrict__ partials /* [B_NBLK][4] */)
{
    __shared__ float red[4 * 4];

    const int t   = threadIdx.x;
    const int w   = t >> 6;            // wave 0..3 -> one row each
    const int L   = t & 63;
    const int blk = blockIdx.x;        // 4096
    const int b   = blk >> 7;          // image
    const int y   = (blk & 127) * 4 + w;
    const int c0  = 8 * L;             // lane owns cols [c0, c0+8)

    const float* rowV = V      + (size_t)b * HH * WW + (size_t)y * WW;
    const float* rowT = target + (size_t)b * HH * WW + (size_t)y * WW;
    const float* rowP = pred   + (size_t)b * HH * WW + (size_t)y * WW;

    const float m_u1 = (L >= 1) ? 1.f : 0.f;
    const float m_u2 = (L >= 2) ? 1.f : 0.f;
    const float m_d1 = (L <= 62) ? 1.f : 0.f;
    const float m_d2 = (L <= 61) ? 1.f : 0.f;

    float4 vA = ld4(rowV, c0), vB = ld4(rowV, c0 + 4);
    float4 tA = ld4(rowT, c0), tB = ld4(rowT, c0 + 4);
    float4 pA = ld4(rowP, c0), pB = ld4(rowP, c0 + 4);

    float own  = vA.x + vA.y + vA.z + vA.w + vB.x + vB.y + vB.z + vB.w;
    float own7 = own - vA.x;
    float s0 = own
             + m_u2 * __shfl_up(own7, 2)
             + m_u1 * __shfl_up(own, 1)
             + m_d1 * __shfl_down(own, 1);
    float a0 = m_d2 * __shfl_down(vA.x, 2);
    float a1 = m_d2 * __shfl_down(vA.y, 2);
    float a2 = m_d2 * __shfl_down(vA.z, 2);
    float a3 = m_d2 * __shfl_down(vA.w, 2);
    float a4 = m_d2 * __shfl_down(vB.x, 2);
    float a5 = m_d2 * __shfl_down(vB.y, 2);
    float a6 = m_d2 * __shfl_down(vB.z, 2);
    float q0 = m_u2 * __shfl_up(vA.y, 2);
    float q1 = m_u2 * __shfl_up(vA.z, 2);
    float q2 = m_u2 * __shfl_up(vA.w, 2);
    float q3 = m_u2 * __shfl_up(vB.x, 2);
    float q4 = m_u2 * __shfl_up(vB.y, 2);
    float q5 = m_u2 * __shfl_up(vB.z, 2);
    float q6 = m_u2 * __shfl_up(vB.w, 2);

    float s1 = s0 + a0 - q0;
    float s2 = s1 + a1 - q1;
    float s3 = s2 + a2 - q2;
    float s4 = s3 + a3 - q3;
    float s5 = s4 + a4 - q4;
    float s6 = s5 + a5 - q5;
    float s7 = s6 + a6 - q6;

    float aw = 0.f, ab = 0.f, ai = 0.f, au = 0.f;
    accum_px(s0, tA.x, pA.x, aw, ab, ai, au);
    accum_px(s1, tA.y, pA.y, aw, ab, ai, au);
    accum_px(s2, tA.z, pA.z, aw, ab, ai, au);
    accum_px(s3, tA.w, pA.w, aw, ab, ai, au);
    accum_px(s4, tB.x, pB.x, aw, ab, ai, au);
    accum_px(s5, tB.y, pB.y, aw, ab, ai, au);
    accum_px(s6, tB.z, pB.z, aw, ab, ai, au);
    accum_px(s7, tB.w, pB.w, aw, ab, ai, au);

    aw = wave_reduce(aw);
    ab = wave_reduce(ab);
    ai = wave_reduce(ai);
    au = wave_reduce(au);
    if (L == 0) {
        red[w * 4 + 0] = aw;
        red[w * 4 + 1] = ab;
        red[w * 4 + 2] = ai;
        red[w * 4 + 3] = au;
    }
    __syncthreads();
    if (t == 0) {
        float ww = 0.f, bc = 0.f, in = 0.f, un = 0.f;
        #pragma unroll
        for (int i = 0; i < 4; ++i) {
            ww += red[i * 4 + 0];
            bc += red[i * 4 + 1];
            in += red[i * 4 + 2];
            un += red[i * 4 + 3];
        }
        float* o = partials + (size_t)blk * 4;
        o[0] = ww; o[1] = bc; o[2] = in; o[3] = un;
    }
}

// ------------------------------- finalize ------------------------------------
__global__ __launch_bounds__(256) void structure_loss_finalize(
    const float* __restrict__ partials, float* __restrict__ out)
{
    // partials: [4096][4]; image b owns entries [b*128, (b+1)*128)
    const int t  = threadIdx.x;
    const int b  = t >> 3;           // image (8 threads per image)
    const int i0 = (t & 7) * 16;     // 16 partial-entries per thread
    float w = 0.f, bc = 0.f, in = 0.f, un = 0.f;
    #pragma unroll
    for (int k = 0; k < 16; ++k) {
        float4 v = *(const float4*)(partials + ((size_t)(b * 128 + i0 + k)) * 4);
        w += v.x; bc += v.y; in += v.z; un += v.w;
    }
    #pragma unroll
    for (int off = 4; off > 0; off >>= 1) {
        w  += __shfl_down(w, off);
        bc += __shfl_down(bc, off);
        in += __shfl_down(in, off);
        un += __shfl_down(un, off);
    }
    __shared__ float vals[32];
    if ((t & 7) == 0) {
        float wbce = bc / w;
        float wiou = 1.0f - (in + 1.0f) / (un - in + 1.0f);
        vals[b] = wbce + wiou;
    }
    __syncthreads();
    if (t < 64) {
        float v = (t < 32) ? vals[t] : 0.0f;
        v = wave_reduce(v);
        if (t == 0) out[0] = v / (float)BB;
    }
}

extern "C" void kernel_launch(void* const* d_in, const int* in_sizes, int n_in,
                              void* d_out, int out_size, void* d_ws, size_t ws_size,
                              hipStream_t stream) {
    const float* pred   = (const float*)d_in[0];
    const float* target = (const float*)d_in[1];
    float* out = (float*)d_out;

    float* V        = (float*)d_ws;                                      // 33.55 MB
    float* partials = (float*)((char*)d_ws + (size_t)BB * HH * WW * 4);  // 64 KB

    vsum_kernel<<<A_NBLK, 256, 0, stream>>>(target, V);
    loss_kernel<<<B_NBLK, 256, 0, stream>>>(pred, target, V, partials);
    structure_loss_finalize<<<1, 256, 0, stream>>>(partials, out);
}

// Round 11
// 111.507 us; speedup vs baseline: 1.1419x; 1.0458x over previous
//
#include <hip/hip_runtime.h>
#include <math.h>

// StructureLoss: B=32, C=1, H=W=512, 31x31 box filter, pad 15
#define BB 32
#define HH 512
#define WW 512
#define KK 31
#define PP 15
#define WROWS 4                       // rows per wave
#define HSEG 16                       // rows per block (4 waves x 4 rows)
#define BLOCKS_PER_IMG (HH / HSEG)    // 32
#define NBLOCKS (BB * BLOCKS_PER_IMG) // 1024 -> 4 blocks/CU, 16 waves/CU
#define NTHREADS 256
#define NBAND 11                      // 4-row bands: rows y0-16 .. y0+27

__device__ inline float wave_reduce(float v) {
    #pragma unroll
    for (int off = 32; off > 0; off >>= 1) v += __shfl_down(v, off);
    return v;
}

// 3 transcendentals/px: e=exp(-|x|), r=rcp(1+e) -> sigmoid = r or 1-r,
// log1p(e) = -log(r)
__device__ inline void accum_px(float s, float tg, float x,
                                float& aw, float& ab, float& ai, float& au) {
    const float inv = 1.0f / (float)(KK * KK);
    float pooled = s * inv;
    float weit = fmaf(5.0f, fabsf(pooled - tg), 1.0f);
    float e  = __expf(-fabsf(x));
    float rr = __builtin_amdgcn_rcpf(1.0f + e);
    float bce = fmaxf(x, 0.0f) - x * tg - __logf(rr);
    float p  = (x >= 0.0f) ? rr : (1.0f - rr);
    aw += weit;
    ab = fmaf(weit, bce, ab);
    ai = fmaf(p * tg, weit, ai);
    au = fmaf(p + tg, weit, au);
}

__device__ inline float4 ld4(const float* base, int y, int c) {
    return *(const float4*)(base + (size_t)y * WW + c);
}
// row-clamped load, zeroed if row OOB (y is wave-uniform)
__device__ inline float4 ld4z(const float* base, int y, int c) {
    int yc = min(max(y, 0), HH - 1);
    float4 v = *(const float4*)(base + (size_t)yc * WW + c);
    if (y < 0 || y >= HH) v = make_float4(0.f, 0.f, 0.f, 0.f);
    return v;
}
__device__ inline float4 f4add(float4 a, float4 b) {
    return make_float4(a.x + b.x, a.y + b.y, a.z + b.z, a.w + b.w);
}
__device__ inline float4 f4sub(float4 a, float4 b) {
    return make_float4(a.x - b.x, a.y - b.y, a.z - b.z, a.w - b.w);
}

__global__ __launch_bounds__(NTHREADS, 4) void structure_loss_main(
    const float* __restrict__ pred, const float* __restrict__ target,
    float* __restrict__ partials /* [NBLOCKS][4] */)
{
    __shared__ float bands[NBAND][WW];   // 4-row band sums, 22.5 KB
    __shared__ float red[4 * 4];

    const int t   = threadIdx.x;
    const int w   = t >> 6;            // wave 0..3
    const int L   = t & 63;            // lane
    const int blk = blockIdx.x;
    const int b   = blk >> 5;          // image
    const int seg = blk & 31;          // 16-row segment
    const int y0  = seg * HSEG;        // block's first out row
    const int yw  = y0 + w * WROWS;    // wave's first out row
    const int c0  = 8 * L;             // lane owns cols [c0, c0+8)

    const float* tb = target + (size_t)b * HH * WW;
    const float* pb = pred   + (size_t)b * HH * WW;

    // edge masks for cross-lane halo (exact zero padding at row ends)
    const float m_u1 = (L >= 1) ? 1.f : 0.f;
    const float m_u2 = (L >= 2) ? 1.f : 0.f;
    const float m_d1 = (L <= 62) ? 1.f : 0.f;
    const float m_d2 = (L <= 61) ? 1.f : 0.f;

    // ---- cooperative band build: band k = sum of rows y0-16+4k .. +3 ----
    // waves 0..2 build 3 bands each, wave 3 builds 2 (k = 3w + kb < 11)
    #pragma unroll
    for (int kb = 0; kb < 3; ++kb) {
        int k = 3 * w + kb;
        if (k < NBAND) {
            int yb = y0 - 16 + 4 * k;
            float4 sA = make_float4(0,0,0,0), sB = sA;
            #pragma unroll
            for (int j = 0; j < 4; ++j) {
                sA = f4add(sA, ld4z(tb, yb + j, c0));
                sB = f4add(sB, ld4z(tb, yb + j, c0 + 4));
            }
            *(float4*)&bands[k][c0]     = sA;
            *(float4*)&bands[k][c0 + 4] = sB;
        }
    }

    // prologue global loads (independent of LDS; in flight across the barrier)
    float4 tgA = ld4(tb, yw, c0),  tgB = ld4(tb, yw, c0 + 4);
    float4 prA = ld4(pb, yw, c0),  prB = ld4(pb, yw, c0 + 4);
    float4 adA = ld4z(tb, yw + PP + 1, c0), adB = ld4z(tb, yw + PP + 1, c0 + 4);
    float4 sbA = ld4z(tb, yw - PP, c0),     sbB = ld4z(tb, yw - PP, c0 + 4);
    float4 exA = ld4z(tb, yw - 16, c0),     exB = ld4z(tb, yw - 16, c0 + 4);

    __syncthreads();   // the only barrier before the final reduction

    // ---- assemble initial window rows [yw-15, yw+15]:
    //      sum bands w..w+7 (rows yw-16..yw+15) minus raw row yw-16 ----
    float4 vsA = make_float4(0,0,0,0), vsB = vsA;
    #pragma unroll
    for (int k = 0; k < 8; ++k) {
        vsA = f4add(vsA, *(const float4*)&bands[w + k][c0]);
        vsB = f4add(vsB, *(const float4*)&bands[w + k][c0 + 4]);
    }
    vsA = f4sub(vsA, exA);
    vsB = f4sub(vsB, exB);

    float aw = 0.f, ab = 0.f, ai = 0.f, au = 0.f;

    #pragma unroll
    for (int r = 0; r < WROWS; ++r) {
        // prefetch next row (in flight across this row's compute; no barriers)
        float4 tgA2, tgB2, prA2, prB2, adA2, adB2, sbA2, sbB2;
        if (r < WROWS - 1) {
            int y = yw + r + 1;
            tgA2 = ld4(tb, y, c0);  tgB2 = ld4(tb, y, c0 + 4);
            prA2 = ld4(pb, y, c0);  prB2 = ld4(pb, y, c0 + 4);
            adA2 = ld4z(tb, y + PP + 1, c0); adB2 = ld4z(tb, y + PP + 1, c0 + 4);
            sbA2 = ld4z(tb, y - PP, c0);     sbB2 = ld4z(tb, y - PP, c0 + 4);
        }

        // ---- horizontal 31-window via cross-lane (17 shuffles, no LDS) ----
        float own  = vsA.x + vsA.y + vsA.z + vsA.w + vsB.x + vsB.y + vsB.z + vsB.w;
        float own7 = own - vsA.x;   // neighbor's cols 1..7 when shifted
        float s0 = own
                 + m_u2 * __shfl_up(own7, 2)
                 + m_u1 * __shfl_up(own, 1)
                 + m_d1 * __shfl_down(own, 1);
        float a0 = m_d2 * __shfl_down(vsA.x, 2);
        float a1 = m_d2 * __shfl_down(vsA.y, 2);
        float a2 = m_d2 * __shfl_down(vsA.z, 2);
        float a3 = m_d2 * __shfl_down(vsA.w, 2);
        float a4 = m_d2 * __shfl_down(vsB.x, 2);
        float a5 = m_d2 * __shfl_down(vsB.y, 2);
        float a6 = m_d2 * __shfl_down(vsB.z, 2);
        float q0 = m_u2 * __shfl_up(vsA.y, 2);
        float q1 = m_u2 * __shfl_up(vsA.z, 2);
        float q2 = m_u2 * __shfl_up(vsA.w, 2);
        float q3 = m_u2 * __shfl_up(vsB.x, 2);
        float q4 = m_u2 * __shfl_up(vsB.y, 2);
        float q5 = m_u2 * __shfl_up(vsB.z, 2);
        float q6 = m_u2 * __shfl_up(vsB.w, 2);

        float s1 = s0 + a0 - q0;
        float s2 = s1 + a1 - q1;
        float s3 = s2 + a2 - q2;
        float s4 = s3 + a3 - q3;
        float s5 = s4 + a4 - q4;
        float s6 = s5 + a5 - q5;
        float s7 = s6 + a6 - q6;

        accum_px(s0, tgA.x, prA.x, aw, ab, ai, au);
        accum_px(s1, tgA.y, prA.y, aw, ab, ai, au);
        accum_px(s2, tgA.z, prA.z, aw, ab, ai, au);
        accum_px(s3, tgA.w, prA.w, aw, ab, ai, au);
        accum_px(s4, tgB.x, prB.x, aw, ab, ai, au);
        accum_px(s5, tgB.y, prB.y, aw, ab, ai, au);
        accum_px(s6, tgB.z, prB.z, aw, ab, ai, au);
        accum_px(s7, tgB.w, prB.w, aw, ab, ai, au);

        // vertical slide to next row
        vsA.x += adA.x - sbA.x; vsA.y += adA.y - sbA.y;
        vsA.z += adA.z - sbA.z; vsA.w += adA.w - sbA.w;
        vsB.x += adB.x - sbB.x; vsB.y += adB.y - sbB.y;
        vsB.z += adB.z - sbB.z; vsB.w += adB.w - sbB.w;

        tgA = tgA2; tgB = tgB2; prA = prA2; prB = prB2;
        adA = adA2; adB = adB2; sbA = sbA2; sbB = sbB2;
    }

    // block reduction
    aw = wave_reduce(aw);
    ab = wave_reduce(ab);
    ai = wave_reduce(ai);
    au = wave_reduce(au);
    if (L == 0) {
        red[w * 4 + 0] = aw;
        red[w * 4 + 1] = ab;
        red[w * 4 + 2] = ai;
        red[w * 4 + 3] = au;
    }
    __syncthreads();
    if (t == 0) {
        float ww = 0.f, bc = 0.f, in = 0.f, un = 0.f;
        #pragma unroll
        for (int i = 0; i < 4; ++i) {
            ww += red[i * 4 + 0];
            bc += red[i * 4 + 1];
            in += red[i * 4 + 2];
            un += red[i * 4 + 3];
        }
        float* o = partials + (size_t)blk * 4;
        o[0] = ww; o[1] = bc; o[2] = in; o[3] = un;
    }
}

__global__ __launch_bounds__(256) void structure_loss_finalize(
    const float* __restrict__ partials, float* __restrict__ out)
{
    // partials: [1024][4]; image b owns entries [b*32, (b+1)*32)
    const int t  = threadIdx.x;      // 256 threads
    const int b  = t >> 3;           // image 0..31  (8 threads per image)
    const int i0 = (t & 7) * 4;      // 4 partial-entries per thread
    float w = 0.f, bc = 0.f, in = 0.f, un = 0.f;
    #pragma unroll
    for (int k = 0; k < 4; ++k) {
        float4 v = *(const float4*)(partials + ((size_t)(b * 32 + i0 + k)) * 4);
        w += v.x; bc += v.y; in += v.z; un += v.w;
    }
    #pragma unroll
    for (int off = 4; off > 0; off >>= 1) {
        w  += __shfl_down(w, off);
        bc += __shfl_down(bc, off);
        in += __shfl_down(in, off);
        un += __shfl_down(un, off);
    }
    __shared__ float vals[32];
    if ((t & 7) == 0) {
        float wbce = bc / w;
        float wiou = 1.0f - (in + 1.0f) / (un - in + 1.0f);
        vals[b] = wbce + wiou;
    }
    __syncthreads();
    if (t < 64) {
        float v = (t < 32) ? vals[t] : 0.0f;
        v = wave_reduce(v);
        if (t == 0) out[0] = v / (float)BB;
    }
}

extern "C" void kernel_launch(void* const* d_in, const int* in_sizes, int n_in,
                              void* d_out, int out_size, void* d_ws, size_t ws_size,
                              hipStream_t stream) {
    const float* pred   = (const float*)d_in[0];
    const float* target = (const float*)d_in[1];
    float* out      = (float*)d_out;
    float* partials = (float*)d_ws;   // NBLOCKS*4 floats = 16 KB

    structure_loss_main<<<NBLOCKS, NTHREADS, 0, stream>>>(pred, target, partials);
    structure_loss_finalize<<<1, 256, 0, stream>>>(partials, out);
}